// Round 6
// baseline (471.748 us; speedup 1.0000x reference)
//
#include <hip/hip_runtime.h>
#include <math.h>

#define NN 100000
#define EE 3200000
#define FF 128
#define HH 6
#define CC 10
#define GG 512
#define NBUCK 196          // ceil(NN/512); bucket = dst >> 9
#define BCAP 20000         // per-bucket edge capacity (mean 16327, sigma 128 -> +28 sigma)
#define PTILE 2048
#define MAXIT 20           // 20*1024 = 20480 >= BCAP

typedef _Float16 half8 __attribute__((ext_vector_type(8)));

// ========== init per-bucket cursors to fixed bases ==========
__global__ __launch_bounds__(256) void k_initcur(int* __restrict__ gcur) {
    int t = threadIdx.x;
    if (t < NBUCK) gcur[t] = t * BCAP;
}

// ========== partition packed edges into bucket runs (single-atomic rank) ==========
__global__ __launch_bounds__(256) void k_partition(const int* __restrict__ src,
                                                   const int* __restrict__ dst,
                                                   int* __restrict__ gcur,
                                                   int* __restrict__ part) {
    __shared__ int lcnt[NBUCK], lbase[NBUCK];
    int t = threadIdx.x;
    for (int i = t; i < NBUCK; i += 256) lcnt[i] = 0;
    __syncthreads();
    int base = blockIdx.x * PTILE;
    int d[8], s[8], r[8];
#pragma unroll
    for (int k = 0; k < 8; ++k) {
        int e = base + (k << 8) + t;
        d[k] = (e < EE) ? dst[e] : -1;
        s[k] = (e < EE) ? src[e] : 0;
    }
#pragma unroll
    for (int k = 0; k < 8; ++k)
        if (d[k] >= 0) r[k] = atomicAdd(&lcnt[d[k] >> 9], 1);
    __syncthreads();
    for (int i = t; i < NBUCK; i += 256)
        lbase[i] = lcnt[i] ? atomicAdd(&gcur[i], lcnt[i]) : 0;
    __syncthreads();
#pragma unroll
    for (int k = 0; k < 8; ++k) {
        if (d[k] >= 0) {
            int bkt = d[k] >> 9;
            part[lbase[bkt] + r[k]] = (s[k] << 9) | (d[k] & 511);
        }
    }
}

// ========== per-bucket counting sort, single part read ==========
__global__ __launch_bounds__(1024) void k_bucketfill(const int* __restrict__ gcur,
                                                     const int* __restrict__ part,
                                                     int* __restrict__ csr,
                                                     int* __restrict__ rowptr,
                                                     int* __restrict__ counts,
                                                     float* __restrict__ dinv) {
    __shared__ int cnt[512];
    __shared__ int wsum[16];
    int t = threadIdx.x, b = blockIdx.x;
    int nbase = b << 9;
    int ebase = b * BCAP, ecount = gcur[b] - ebase;
    if (t < 512) cnt[t] = 0;
    __syncthreads();
    int p[MAXIT], r[MAXIT];
#pragma unroll
    for (int it = 0; it < MAXIT; ++it) {
        int j = (it << 10) + t;
        p[it] = (j < ecount) ? part[ebase + j] : -1;
    }
#pragma unroll
    for (int it = 0; it < MAXIT; ++it)
        if (p[it] >= 0) r[it] = atomicAdd(&cnt[p[it] & 511], 1);
    __syncthreads();
    // exclusive scan of cnt[512] (waves 8-15 carry zeros)
    int c = (t < 512) ? cnt[t] : 0;
    int lane = t & 63, wv = t >> 6;
    int v = c;
#pragma unroll
    for (int off = 1; off < 64; off <<= 1) {
        int u = __shfl_up(v, off, 64);
        if (lane >= off) v += u;
    }
    if (lane == 63) wsum[wv] = v;
    __syncthreads();
    int acc = 0;
    for (int k = 0; k < wv; ++k) acc += wsum[k];
    int excl = ebase + acc + v - c;
    if (t < 512) {
        int node = nbase + t;
        if (node < NN) {
            rowptr[node] = excl;
            counts[node] = c;
            dinv[node] = rsqrtf((float)c + 1.0f);
        }
        cnt[t] = excl;   // reuse as per-node base
    }
    __syncthreads();
#pragma unroll
    for (int it = 0; it < MAXIT; ++it)
        if (p[it] >= 0) csr[cnt[p[it] & 511] + r[it]] = p[it] >> 9;
}

// ========== layer 1: hs = dinv * (x @ W1) -> half, 8-pad; 4 lanes per node ==========
__global__ __launch_bounds__(256) void k_xw1(const float* __restrict__ x,
                                             const float* __restrict__ W,
                                             const float* __restrict__ dinv,
                                             _Float16* __restrict__ hs) {
    __shared__ float sW[FF * HH];
    for (int i = threadIdx.x; i < FF * HH; i += 256) sW[i] = W[i];
    __syncthreads();
    int node = blockIdx.x * 64 + (threadIdx.x >> 2);
    int sub  = threadIdx.x & 3;
    if (node >= NN) return;
    const float4* xr = (const float4*)(x + (size_t)node * FF + sub * 32);
    float acc[HH];
#pragma unroll
    for (int c = 0; c < HH; ++c) acc[c] = 0.f;
#pragma unroll
    for (int q = 0; q < 8; ++q) {
        float4 v = xr[q];
        int k = sub * 32 + q * 4;
        const float* w0 = &sW[(k + 0) * HH];
        const float* w1 = &sW[(k + 1) * HH];
        const float* w2 = &sW[(k + 2) * HH];
        const float* w3 = &sW[(k + 3) * HH];
#pragma unroll
        for (int c = 0; c < HH; ++c)
            acc[c] += v.x * w0[c] + v.y * w1[c] + v.z * w2[c] + v.w * w3[c];
    }
#pragma unroll
    for (int c = 0; c < HH; ++c) {
        acc[c] += __shfl_xor(acc[c], 1, 64);
        acc[c] += __shfl_xor(acc[c], 2, 64);
    }
    if (sub == 0) {
        float di = dinv[node];
        half8 o;
#pragma unroll
        for (int c = 0; c < HH; ++c) o[c] = (_Float16)(di * acc[c]);
        o[6] = (_Float16)0.f; o[7] = (_Float16)0.f;
        *((half8*)(hs + (size_t)node * 8)) = o;
    }
}

// ===== fused gather + next mm, 4 lanes per node =====
template <int HON, int HPOH>
__global__ __launch_bounds__(256) void k_gf(const int* __restrict__ rowptr,
                                            const int* __restrict__ counts,
                                            const int* __restrict__ csr,
                                            const float* __restrict__ dinv,
                                            const _Float16* __restrict__ hs,
                                            const float* __restrict__ bias,
                                            const float* __restrict__ Wn,
                                            _Float16* __restrict__ outn) {
    __shared__ float sW[HH * HON];
    if (threadIdx.x < HH * HON) sW[threadIdx.x] = Wn[threadIdx.x];
    __syncthreads();
    int node = blockIdx.x * 64 + (threadIdx.x >> 2);
    int sub  = threadIdx.x & 3;
    if (node >= NN) return;
    int st = rowptr[node], cnt = counts[node];
    float a[HH];
    if (sub == 0) {
        half8 v = *((const half8*)(hs + (size_t)node * 8));
#pragma unroll
        for (int c = 0; c < HH; ++c) a[c] = (float)v[c];
    } else {
#pragma unroll
        for (int c = 0; c < HH; ++c) a[c] = 0.f;
    }
    int j = st + sub, end = st + cnt;
    for (; j + 4 < end; j += 8) {
        int s0 = csr[j], s1 = csr[j + 4];
        half8 v0 = *((const half8*)(hs + (size_t)s0 * 8));
        half8 v1 = *((const half8*)(hs + (size_t)s1 * 8));
#pragma unroll
        for (int c = 0; c < HH; ++c) a[c] += (float)v0[c] + (float)v1[c];
    }
    if (j < end) {
        int s = csr[j];
        half8 v = *((const half8*)(hs + (size_t)s * 8));
#pragma unroll
        for (int c = 0; c < HH; ++c) a[c] += (float)v[c];
    }
#pragma unroll
    for (int c = 0; c < HH; ++c) {
        a[c] += __shfl_xor(a[c], 1, 64);
        a[c] += __shfl_xor(a[c], 2, 64);
    }
    if (sub == 0) {
        float di = dinv[node];
        float h[HH];
#pragma unroll
        for (int c = 0; c < HH; ++c) h[c] = fmaxf(di * a[c] + bias[c], 0.f);
        half8 o[HPOH / 8];
#pragma unroll
        for (int c = 0; c < HPOH; ++c) {
            float s = 0.f;
            if (c < HON) {
#pragma unroll
                for (int k = 0; k < HH; ++k) s += h[k] * sW[k * HON + c];
                o[c / 8][c % 8] = (_Float16)(di * s);
            } else {
                o[c / 8][c % 8] = (_Float16)0.f;
            }
        }
        half8* op = (half8*)(outn + (size_t)node * HPOH);
#pragma unroll
        for (int q = 0; q < HPOH / 8; ++q) op[q] = o[q];
    }
}

// ===== last gather + fused mean-pool accumulate (atomics into G*C) =====
__global__ __launch_bounds__(256) void k_glast(const int* __restrict__ rowptr,
                                               const int* __restrict__ counts,
                                               const int* __restrict__ csr,
                                               const float* __restrict__ dinv,
                                               const _Float16* __restrict__ hs,
                                               const float* __restrict__ bias,
                                               const int* __restrict__ batch,
                                               float* __restrict__ gpool) {
    int node = blockIdx.x * 64 + (threadIdx.x >> 2);
    int sub  = threadIdx.x & 3;
    if (node >= NN) return;
    int st = rowptr[node], cnt = counts[node];
    float a[CC];
    if (sub == 0) {
        const half8* p = (const half8*)(hs + (size_t)node * 16);
        half8 v0 = p[0], v1 = p[1];
#pragma unroll
        for (int c = 0; c < 8; ++c) a[c] = (float)v0[c];
        a[8] = (float)v1[0]; a[9] = (float)v1[1];
    } else {
#pragma unroll
        for (int c = 0; c < CC; ++c) a[c] = 0.f;
    }
    int j = st + sub, end = st + cnt;
    for (; j + 4 < end; j += 8) {
        int s0 = csr[j], s1 = csr[j + 4];
        const half8* p0 = (const half8*)(hs + (size_t)s0 * 16);
        const half8* p1 = (const half8*)(hs + (size_t)s1 * 16);
        half8 x0 = p0[0], y0 = p0[1], x1 = p1[0], y1 = p1[1];
#pragma unroll
        for (int c = 0; c < 8; ++c) a[c] += (float)x0[c] + (float)x1[c];
        a[8] += (float)y0[0] + (float)y1[0];
        a[9] += (float)y0[1] + (float)y1[1];
    }
    if (j < end) {
        int s = csr[j];
        const half8* p = (const half8*)(hs + (size_t)s * 16);
        half8 x0 = p[0], y0 = p[1];
#pragma unroll
        for (int c = 0; c < 8; ++c) a[c] += (float)x0[c];
        a[8] += (float)y0[0]; a[9] += (float)y0[1];
    }
#pragma unroll
    for (int c = 0; c < CC; ++c) {
        a[c] += __shfl_xor(a[c], 1, 64);
        a[c] += __shfl_xor(a[c], 2, 64);
    }
    if (sub == 0) {
        float di = dinv[node];
        int g = batch[node];
        float* gp = gpool + (size_t)g * CC;
#pragma unroll
        for (int c = 0; c < CC; ++c) {
            float rv = fmaxf(di * a[c] + bias[c], 0.f);
            atomicAdd(&gp[c], rv);
        }
    }
}

// ========== graph boundaries via binary search (batch is sorted) ==========
__global__ __launch_bounds__(256) void k_bounds(const int* __restrict__ batch,
                                                int* __restrict__ bounds) {
    int g = blockIdx.x * 256 + threadIdx.x;
    if (g > GG) return;
    int lo = 0, hi = NN;
    while (lo < hi) {
        int mid = (lo + hi) >> 1;
        if (batch[mid] < g) lo = mid + 1; else hi = mid;
    }
    bounds[g] = lo;
}

// ========== finalize: mean + log_softmax, one thread per graph ==========
__global__ __launch_bounds__(256) void k_poolfin(const float* __restrict__ gpool,
                                                 const int* __restrict__ bounds,
                                                 float* __restrict__ out) {
    int g = blockIdx.x * 256 + threadIdx.x;
    if (g >= GG) return;
    float cntf = fmaxf((float)(bounds[g + 1] - bounds[g]), 1.0f);
    float tot[CC];
    float m = -1e30f;
#pragma unroll
    for (int c = 0; c < CC; ++c) {
        tot[c] = gpool[(size_t)g * CC + c] / cntf;
        m = fmaxf(m, tot[c]);
    }
    float ss = 0.f;
#pragma unroll
    for (int c = 0; c < CC; ++c) ss += expf(tot[c] - m);
    float lse = logf(ss) + m;
#pragma unroll
    for (int c = 0; c < CC; ++c) out[(size_t)g * CC + c] = tot[c] - lse;
}

extern "C" void kernel_launch(void* const* d_in, const int* in_sizes, int n_in,
                              void* d_out, int out_size, void* d_ws, size_t ws_size,
                              hipStream_t stream) {
    const float* x     = (const float*)d_in[0];
    const int*   ei    = (const int*)d_in[1];
    const int*   batch = (const int*)d_in[2];
    const float* W1 = (const float*)d_in[3];
    const float* b1 = (const float*)d_in[4];
    const float* W2 = (const float*)d_in[5];
    const float* b2 = (const float*)d_in[6];
    const float* W3 = (const float*)d_in[7];
    const float* b3 = (const float*)d_in[8];
    const float* W4 = (const float*)d_in[9];
    const float* b4 = (const float*)d_in[10];
    const float* Wf = (const float*)d_in[11];
    const float* bf = (const float*)d_in[12];
    float* out = (float*)d_out;

    const int* src = ei;
    const int* dst = ei + EE;

    // -------- workspace layout (4B units) --------
    int*   iw     = (int*)d_ws;
    int*   csr    = iw;                        // [3,920,000] bucket-strided
    int*   rowptr = csr + 3920000;             // [100,352]
    int*   counts = rowptr + 100352;           // [100,352]
    float* dinv   = (float*)(counts + 100352); // [100,352]
    int*   gcur   = (int*)(dinv + 100352);     // [256]
    int*   bounds = gcur + 256;                // [640]
    float* gpool  = (float*)(bounds + 640);    // [5,376]  G*C accumulators
    int*   part   = (int*)(gpool + 5376);      // [3,920,000], overlaid after bucketfill:
    _Float16* hsA = (_Float16*)part;           //   [1,605,632 halves]
    _Float16* hsB = hsA + 1605632;             //   [1,605,632 halves]

    const int TB = (EE + PTILE - 1) / PTILE;   // 1563
    const int GB = (NN + 63) / 64;             // 1563 (4 lanes per node)

    // -------- CSR build --------
    k_initcur<<<1, 256, 0, stream>>>(gcur);
    hipMemsetAsync(gpool, 0, GG * CC * sizeof(float), stream);
    k_bounds<<<3, 256, 0, stream>>>(batch, bounds);
    k_partition<<<TB, 256, 0, stream>>>(src, dst, gcur, part);
    k_bucketfill<<<NBUCK, 1024, 0, stream>>>(gcur, part, csr, rowptr, counts, dinv);

    // -------- layers --------
    k_xw1<<<GB, 256, 0, stream>>>(x, W1, dinv, hsA);                                       // hs1
    k_gf<HH, 8><<<GB, 256, 0, stream>>>(rowptr, counts, csr, dinv, hsA, b1, W2, hsB);      // hs2
    k_gf<HH, 8><<<GB, 256, 0, stream>>>(rowptr, counts, csr, dinv, hsB, b2, W3, hsA);      // hs3
    k_gf<HH, 8><<<GB, 256, 0, stream>>>(rowptr, counts, csr, dinv, hsA, b3, W4, hsB);      // hs4
    k_gf<CC, 16><<<GB, 256, 0, stream>>>(rowptr, counts, csr, dinv, hsB, b4, Wf, hsA);     // hs5 (16-pad)
    k_glast<<<GB, 256, 0, stream>>>(rowptr, counts, csr, dinv, hsA, bf, batch, gpool);     // pool accum

    // -------- finalize --------
    k_poolfin<<<2, 256, 0, stream>>>(gpool, bounds, out);
}

// Round 7
// 224.237 us; speedup vs baseline: 2.1038x; 2.1038x over previous
//
#include <hip/hip_runtime.h>
#include <math.h>

#define NN 100000
#define EE 3200000
#define FF 128
#define HH 6
#define CC 10
#define GG 512
#define NBUCK 196          // ceil(NN/512); bucket = dst >> 9
#define BCAP 20000         // per-bucket edge capacity (mean 16327, sigma 128 -> +28 sigma)
#define PTILE 2048
#define MAXIT 20           // 20*1024 = 20480 >= BCAP

typedef _Float16 half8 __attribute__((ext_vector_type(8)));

// ========== setup: bucket cursors + graph bounds (one launch) ==========
__global__ __launch_bounds__(256) void k_setup(const int* __restrict__ batch,
                                               int* __restrict__ gcur,
                                               int* __restrict__ bounds) {
    int i = blockIdx.x * 256 + threadIdx.x;
    if (i < NBUCK) gcur[i] = i * BCAP;
    if (i <= GG) {
        int lo = 0, hi = NN;
        while (lo < hi) {
            int mid = (lo + hi) >> 1;
            if (batch[mid] < i) lo = mid + 1; else hi = mid;
        }
        bounds[i] = lo;
    }
}

// ========== partition packed edges into bucket runs (single-atomic rank) ==========
__global__ __launch_bounds__(256) void k_partition(const int* __restrict__ src,
                                                   const int* __restrict__ dst,
                                                   int* __restrict__ gcur,
                                                   int* __restrict__ part) {
    __shared__ int lcnt[NBUCK], lbase[NBUCK];
    int t = threadIdx.x;
    for (int i = t; i < NBUCK; i += 256) lcnt[i] = 0;
    __syncthreads();
    int base = blockIdx.x * PTILE;
    int d[8], s[8], r[8];
#pragma unroll
    for (int k = 0; k < 8; ++k) {
        int e = base + (k << 8) + t;
        d[k] = (e < EE) ? dst[e] : -1;
        s[k] = (e < EE) ? src[e] : 0;
    }
#pragma unroll
    for (int k = 0; k < 8; ++k)
        if (d[k] >= 0) r[k] = atomicAdd(&lcnt[d[k] >> 9], 1);
    __syncthreads();
    for (int i = t; i < NBUCK; i += 256)
        lbase[i] = lcnt[i] ? atomicAdd(&gcur[i], lcnt[i]) : 0;
    __syncthreads();
#pragma unroll
    for (int k = 0; k < 8; ++k) {
        if (d[k] >= 0) {
            int bkt = d[k] >> 9;
            part[lbase[bkt] + r[k]] = (s[k] << 9) | (d[k] & 511);
        }
    }
}

// ========== per-bucket counting sort, single part read ==========
__global__ __launch_bounds__(1024) void k_bucketfill(const int* __restrict__ gcur,
                                                     const int* __restrict__ part,
                                                     int* __restrict__ csr,
                                                     int* __restrict__ rowptr,
                                                     int* __restrict__ counts,
                                                     float* __restrict__ dinv) {
    __shared__ int cnt[512];
    __shared__ int wsum[16];
    int t = threadIdx.x, b = blockIdx.x;
    int nbase = b << 9;
    int ebase = b * BCAP, ecount = gcur[b] - ebase;
    if (t < 512) cnt[t] = 0;
    __syncthreads();
    int p[MAXIT], r[MAXIT];
#pragma unroll
    for (int it = 0; it < MAXIT; ++it) {
        int j = (it << 10) + t;
        p[it] = (j < ecount) ? part[ebase + j] : -1;
    }
#pragma unroll
    for (int it = 0; it < MAXIT; ++it)
        if (p[it] >= 0) r[it] = atomicAdd(&cnt[p[it] & 511], 1);
    __syncthreads();
    // exclusive scan of cnt[512] (waves 8-15 carry zeros)
    int c = (t < 512) ? cnt[t] : 0;
    int lane = t & 63, wv = t >> 6;
    int v = c;
#pragma unroll
    for (int off = 1; off < 64; off <<= 1) {
        int u = __shfl_up(v, off, 64);
        if (lane >= off) v += u;
    }
    if (lane == 63) wsum[wv] = v;
    __syncthreads();
    int acc = 0;
    for (int k = 0; k < wv; ++k) acc += wsum[k];
    int excl = ebase + acc + v - c;
    if (t < 512) {
        int node = nbase + t;
        if (node < NN) {
            rowptr[node] = excl;
            counts[node] = c;
            dinv[node] = rsqrtf((float)c + 1.0f);
        }
        cnt[t] = excl;   // reuse as per-node base
    }
    __syncthreads();
#pragma unroll
    for (int it = 0; it < MAXIT; ++it)
        if (p[it] >= 0) csr[cnt[p[it] & 511] + r[it]] = p[it] >> 9;
}

// ========== layer 1: hs = dinv * (x @ W1) -> half, 8-pad; 4 lanes per node ==========
__global__ __launch_bounds__(256) void k_xw1(const float* __restrict__ x,
                                             const float* __restrict__ W,
                                             const float* __restrict__ dinv,
                                             _Float16* __restrict__ hs) {
    __shared__ float sW[FF * HH];
    for (int i = threadIdx.x; i < FF * HH; i += 256) sW[i] = W[i];
    __syncthreads();
    int node = blockIdx.x * 64 + (threadIdx.x >> 2);
    int sub  = threadIdx.x & 3;
    if (node >= NN) return;
    const float4* xr = (const float4*)(x + (size_t)node * FF + sub * 32);
    float acc[HH];
#pragma unroll
    for (int c = 0; c < HH; ++c) acc[c] = 0.f;
#pragma unroll
    for (int q = 0; q < 8; ++q) {
        float4 v = xr[q];
        int k = sub * 32 + q * 4;
        const float* w0 = &sW[(k + 0) * HH];
        const float* w1 = &sW[(k + 1) * HH];
        const float* w2 = &sW[(k + 2) * HH];
        const float* w3 = &sW[(k + 3) * HH];
#pragma unroll
        for (int c = 0; c < HH; ++c)
            acc[c] += v.x * w0[c] + v.y * w1[c] + v.z * w2[c] + v.w * w3[c];
    }
#pragma unroll
    for (int c = 0; c < HH; ++c) {
        acc[c] += __shfl_xor(acc[c], 1, 64);
        acc[c] += __shfl_xor(acc[c], 2, 64);
    }
    if (sub == 0) {
        float di = dinv[node];
        half8 o;
#pragma unroll
        for (int c = 0; c < HH; ++c) o[c] = (_Float16)(di * acc[c]);
        o[6] = (_Float16)0.f; o[7] = (_Float16)0.f;
        *((half8*)(hs + (size_t)node * 8)) = o;
    }
}

// ===== fused gather + next mm, 4 lanes per node =====
template <int HON, int HPOH>
__global__ __launch_bounds__(256) void k_gf(const int* __restrict__ rowptr,
                                            const int* __restrict__ counts,
                                            const int* __restrict__ csr,
                                            const float* __restrict__ dinv,
                                            const _Float16* __restrict__ hs,
                                            const float* __restrict__ bias,
                                            const float* __restrict__ Wn,
                                            _Float16* __restrict__ outn) {
    __shared__ float sW[HH * HON];
    if (threadIdx.x < HH * HON) sW[threadIdx.x] = Wn[threadIdx.x];
    __syncthreads();
    int node = blockIdx.x * 64 + (threadIdx.x >> 2);
    int sub  = threadIdx.x & 3;
    if (node >= NN) return;
    int st = rowptr[node], cnt = counts[node];
    float a[HH];
    if (sub == 0) {
        half8 v = *((const half8*)(hs + (size_t)node * 8));
#pragma unroll
        for (int c = 0; c < HH; ++c) a[c] = (float)v[c];
    } else {
#pragma unroll
        for (int c = 0; c < HH; ++c) a[c] = 0.f;
    }
    int j = st + sub, end = st + cnt;
    for (; j + 4 < end; j += 8) {
        int s0 = csr[j], s1 = csr[j + 4];
        half8 v0 = *((const half8*)(hs + (size_t)s0 * 8));
        half8 v1 = *((const half8*)(hs + (size_t)s1 * 8));
#pragma unroll
        for (int c = 0; c < HH; ++c) a[c] += (float)v0[c] + (float)v1[c];
    }
    if (j < end) {
        int s = csr[j];
        half8 v = *((const half8*)(hs + (size_t)s * 8));
#pragma unroll
        for (int c = 0; c < HH; ++c) a[c] += (float)v[c];
    }
#pragma unroll
    for (int c = 0; c < HH; ++c) {
        a[c] += __shfl_xor(a[c], 1, 64);
        a[c] += __shfl_xor(a[c], 2, 64);
    }
    if (sub == 0) {
        float di = dinv[node];
        float h[HH];
#pragma unroll
        for (int c = 0; c < HH; ++c) h[c] = fmaxf(di * a[c] + bias[c], 0.f);
        half8 o[HPOH / 8];
#pragma unroll
        for (int c = 0; c < HPOH; ++c) {
            float s = 0.f;
            if (c < HON) {
#pragma unroll
                for (int k = 0; k < HH; ++k) s += h[k] * sW[k * HON + c];
                o[c / 8][c % 8] = (_Float16)(di * s);
            } else {
                o[c / 8][c % 8] = (_Float16)0.f;
            }
        }
        half8* op = (half8*)(outn + (size_t)node * HPOH);
#pragma unroll
        for (int q = 0; q < HPOH / 8; ++q) op[q] = o[q];
    }
}

// ===== last gather: h5 = relu(dinv*(sum hs5 + self) + bf) -> f32 12-pad =====
__global__ __launch_bounds__(256) void k_glast(const int* __restrict__ rowptr,
                                               const int* __restrict__ counts,
                                               const int* __restrict__ csr,
                                               const float* __restrict__ dinv,
                                               const _Float16* __restrict__ hs,
                                               const float* __restrict__ bias,
                                               float* __restrict__ out) {
    int node = blockIdx.x * 64 + (threadIdx.x >> 2);
    int sub  = threadIdx.x & 3;
    if (node >= NN) return;
    int st = rowptr[node], cnt = counts[node];
    float a[CC];
    if (sub == 0) {
        const half8* p = (const half8*)(hs + (size_t)node * 16);
        half8 v0 = p[0], v1 = p[1];
#pragma unroll
        for (int c = 0; c < 8; ++c) a[c] = (float)v0[c];
        a[8] = (float)v1[0]; a[9] = (float)v1[1];
    } else {
#pragma unroll
        for (int c = 0; c < CC; ++c) a[c] = 0.f;
    }
    int j = st + sub, end = st + cnt;
    for (; j + 4 < end; j += 8) {
        int s0 = csr[j], s1 = csr[j + 4];
        const half8* p0 = (const half8*)(hs + (size_t)s0 * 16);
        const half8* p1 = (const half8*)(hs + (size_t)s1 * 16);
        half8 x0 = p0[0], y0 = p0[1], x1 = p1[0], y1 = p1[1];
#pragma unroll
        for (int c = 0; c < 8; ++c) a[c] += (float)x0[c] + (float)x1[c];
        a[8] += (float)y0[0] + (float)y1[0];
        a[9] += (float)y0[1] + (float)y1[1];
    }
    if (j < end) {
        int s = csr[j];
        const half8* p = (const half8*)(hs + (size_t)s * 16);
        half8 x0 = p[0], y0 = p[1];
#pragma unroll
        for (int c = 0; c < 8; ++c) a[c] += (float)x0[c];
        a[8] += (float)y0[0]; a[9] += (float)y0[1];
    }
#pragma unroll
    for (int c = 0; c < CC; ++c) {
        a[c] += __shfl_xor(a[c], 1, 64);
        a[c] += __shfl_xor(a[c], 2, 64);
    }
    if (sub == 0) {
        float di = dinv[node];
        float r[12];
#pragma unroll
        for (int c = 0; c < 12; ++c)
            r[c] = (c < CC) ? fmaxf(di * a[c] + bias[c], 0.f) : 0.f;
        float4* o = (float4*)(out + (size_t)node * 12);
        o[0] = make_float4(r[0], r[1], r[2], r[3]);
        o[1] = make_float4(r[4], r[5], r[6], r[7]);
        o[2] = make_float4(r[8], r[9], r[10], r[11]);
    }
}

// ========== pool + log_softmax, one block per graph ==========
__global__ __launch_bounds__(256) void k_pool(const float* __restrict__ h,
                                              const int* __restrict__ bounds,
                                              float* __restrict__ out) {
    int g = blockIdx.x;
    int s = bounds[g], e = bounds[g + 1];
    float acc[CC];
#pragma unroll
    for (int c = 0; c < CC; ++c) acc[c] = 0.f;
    for (int i = s + threadIdx.x; i < e; i += 256) {
#pragma unroll
        for (int c = 0; c < CC; ++c) acc[c] += h[(size_t)i * 12 + c];
    }
#pragma unroll
    for (int off = 32; off >= 1; off >>= 1)
#pragma unroll
        for (int c = 0; c < CC; ++c) acc[c] += __shfl_down(acc[c], off, 64);
    __shared__ float sacc[4][CC];
    int wv = threadIdx.x >> 6, lane = threadIdx.x & 63;
    if (lane == 0) {
#pragma unroll
        for (int c = 0; c < CC; ++c) sacc[wv][c] = acc[c];
    }
    __syncthreads();
    if (threadIdx.x == 0) {
        float cnt = fmaxf((float)(e - s), 1.0f);
        float tot[CC];
        float m = -1e30f;
#pragma unroll
        for (int c = 0; c < CC; ++c) {
            tot[c] = (sacc[0][c] + sacc[1][c] + sacc[2][c] + sacc[3][c]) / cnt;
            m = fmaxf(m, tot[c]);
        }
        float ssum = 0.f;
#pragma unroll
        for (int c = 0; c < CC; ++c) ssum += expf(tot[c] - m);
        float lse = logf(ssum) + m;
#pragma unroll
        for (int c = 0; c < CC; ++c) out[(size_t)g * CC + c] = tot[c] - lse;
    }
}

extern "C" void kernel_launch(void* const* d_in, const int* in_sizes, int n_in,
                              void* d_out, int out_size, void* d_ws, size_t ws_size,
                              hipStream_t stream) {
    const float* x     = (const float*)d_in[0];
    const int*   ei    = (const int*)d_in[1];
    const int*   batch = (const int*)d_in[2];
    const float* W1 = (const float*)d_in[3];
    const float* b1 = (const float*)d_in[4];
    const float* W2 = (const float*)d_in[5];
    const float* b2 = (const float*)d_in[6];
    const float* W3 = (const float*)d_in[7];
    const float* b3 = (const float*)d_in[8];
    const float* W4 = (const float*)d_in[9];
    const float* b4 = (const float*)d_in[10];
    const float* Wf = (const float*)d_in[11];
    const float* bf = (const float*)d_in[12];
    float* out = (float*)d_out;

    const int* src = ei;
    const int* dst = ei + EE;

    // -------- workspace layout (4B units) --------
    int*   iw     = (int*)d_ws;
    int*   csr    = iw;                        // [3,920,000] bucket-strided
    int*   rowptr = csr + 3920000;             // [100,352]
    int*   counts = rowptr + 100352;           // [100,352]
    float* dinv   = (float*)(counts + 100352); // [100,352]
    int*   gcur   = (int*)(dinv + 100352);     // [256]
    int*   bounds = gcur + 256;                // [640]
    int*   part   = bounds + 640;              // [3,920,000], overlaid after bucketfill:
    _Float16* hsA = (_Float16*)part;           //   [1,605,632 halves]
    _Float16* hsB = hsA + 1605632;             //   [1,605,632 halves]
    float* h5     = (float*)(hsB + 1605632);   //   [1,204,224 floats]

    const int TB = (EE + PTILE - 1) / PTILE;   // 1563
    const int GB = (NN + 63) / 64;             // 1563 (4 lanes per node)

    // -------- CSR build --------
    k_setup<<<3, 256, 0, stream>>>(batch, gcur, bounds);
    k_partition<<<TB, 256, 0, stream>>>(src, dst, gcur, part);
    k_bucketfill<<<NBUCK, 1024, 0, stream>>>(gcur, part, csr, rowptr, counts, dinv);

    // -------- layers --------
    k_xw1<<<GB, 256, 0, stream>>>(x, W1, dinv, hsA);                                       // hs1
    k_gf<HH, 8><<<GB, 256, 0, stream>>>(rowptr, counts, csr, dinv, hsA, b1, W2, hsB);      // hs2
    k_gf<HH, 8><<<GB, 256, 0, stream>>>(rowptr, counts, csr, dinv, hsB, b2, W3, hsA);      // hs3
    k_gf<HH, 8><<<GB, 256, 0, stream>>>(rowptr, counts, csr, dinv, hsA, b3, W4, hsB);      // hs4
    k_gf<CC, 16><<<GB, 256, 0, stream>>>(rowptr, counts, csr, dinv, hsB, b4, Wf, hsA);     // hs5 (16-pad)
    k_glast<<<GB, 256, 0, stream>>>(rowptr, counts, csr, dinv, hsA, bf, h5);               // h5 f32

    // -------- pool + log_softmax --------
    k_pool<<<GG, 256, 0, stream>>>(h5, bounds, out);
}

// Round 8
// 202.044 us; speedup vs baseline: 2.3349x; 1.1098x over previous
//
#include <hip/hip_runtime.h>
#include <math.h>

#define NN 100000
#define EE 3200000
#define FF 128
#define HH 6
#define CC 10
#define GG 512
#define NBUCK 196          // ceil(NN/512); bucket = dst >> 9
#define BCAP 20000         // per-bucket edge capacity (mean 16327, sigma 128 -> +28 sigma)
#define PTILE 8192
#define MAXIT 20           // 20*1024 = 20480 >= BCAP

typedef _Float16 half8 __attribute__((ext_vector_type(8)));

// ========== setup: bucket cursors + graph bounds (one launch) ==========
__global__ __launch_bounds__(256) void k_setup(const int* __restrict__ batch,
                                               int* __restrict__ gcur,
                                               int* __restrict__ bounds) {
    int i = blockIdx.x * 256 + threadIdx.x;
    if (i < NBUCK) gcur[i] = i * BCAP;
    if (i <= GG) {
        int lo = 0, hi = NN;
        while (lo < hi) {
            int mid = (lo + hi) >> 1;
            if (batch[mid] < i) lo = mid + 1; else hi = mid;
        }
        bounds[i] = lo;
    }
}

// ========== partition packed edges into bucket runs (single-atomic rank) ==========
// 391 blocks x 512 threads, 16 edges/thread -> only 391*196 contended global atomics
__global__ __launch_bounds__(512) void k_partition(const int* __restrict__ src,
                                                   const int* __restrict__ dst,
                                                   int* __restrict__ gcur,
                                                   int* __restrict__ part) {
    __shared__ int lcnt[NBUCK], lbase[NBUCK];
    int t = threadIdx.x;
    if (t < NBUCK) lcnt[t] = 0;
    __syncthreads();
    int base = blockIdx.x * PTILE;
    int d[16], s[16], r[16];
#pragma unroll
    for (int k = 0; k < 16; ++k) {
        int e = base + (k << 9) + t;
        d[k] = (e < EE) ? dst[e] : -1;
        s[k] = (e < EE) ? src[e] : 0;
    }
#pragma unroll
    for (int k = 0; k < 16; ++k)
        if (d[k] >= 0) r[k] = atomicAdd(&lcnt[d[k] >> 9], 1);
    __syncthreads();
    if (t < NBUCK) lbase[t] = lcnt[t] ? atomicAdd(&gcur[t], lcnt[t]) : 0;
    __syncthreads();
#pragma unroll
    for (int k = 0; k < 16; ++k) {
        if (d[k] >= 0) {
            int bkt = d[k] >> 9;
            part[lbase[bkt] + r[k]] = (s[k] << 9) | (d[k] & 511);
        }
    }
}

// ========== per-bucket counting sort, single part read ==========
__global__ __launch_bounds__(1024) void k_bucketfill(const int* __restrict__ gcur,
                                                     const int* __restrict__ part,
                                                     int* __restrict__ csr,
                                                     int* __restrict__ rowptr,
                                                     int* __restrict__ counts,
                                                     float* __restrict__ dinv) {
    __shared__ int cnt[512];
    __shared__ int wsum[16];
    int t = threadIdx.x, b = blockIdx.x;
    int nbase = b << 9;
    int ebase = b * BCAP, ecount = gcur[b] - ebase;
    if (t < 512) cnt[t] = 0;
    __syncthreads();
    int p[MAXIT], r[MAXIT];
#pragma unroll
    for (int it = 0; it < MAXIT; ++it) {
        int j = (it << 10) + t;
        p[it] = (j < ecount) ? part[ebase + j] : -1;
    }
#pragma unroll
    for (int it = 0; it < MAXIT; ++it)
        if (p[it] >= 0) r[it] = atomicAdd(&cnt[p[it] & 511], 1);
    __syncthreads();
    // exclusive scan of cnt[512] (waves 8-15 carry zeros)
    int c = (t < 512) ? cnt[t] : 0;
    int lane = t & 63, wv = t >> 6;
    int v = c;
#pragma unroll
    for (int off = 1; off < 64; off <<= 1) {
        int u = __shfl_up(v, off, 64);
        if (lane >= off) v += u;
    }
    if (lane == 63) wsum[wv] = v;
    __syncthreads();
    int acc = 0;
    for (int k = 0; k < wv; ++k) acc += wsum[k];
    int excl = ebase + acc + v - c;
    if (t < 512) {
        int node = nbase + t;
        if (node < NN) {
            rowptr[node] = excl;
            counts[node] = c;
            dinv[node] = rsqrtf((float)c + 1.0f);
        }
        cnt[t] = excl;   // reuse as per-node base
    }
    __syncthreads();
#pragma unroll
    for (int it = 0; it < MAXIT; ++it)
        if (p[it] >= 0) csr[cnt[p[it] & 511] + r[it]] = p[it] >> 9;
}

// ========== layer 1: hs = dinv * (x @ W1) -> half, 8-pad; 4 lanes per node ==========
__global__ __launch_bounds__(256) void k_xw1(const float* __restrict__ x,
                                             const float* __restrict__ W,
                                             const float* __restrict__ dinv,
                                             _Float16* __restrict__ hs) {
    __shared__ float sW[FF * HH];
    for (int i = threadIdx.x; i < FF * HH; i += 256) sW[i] = W[i];
    __syncthreads();
    int node = blockIdx.x * 64 + (threadIdx.x >> 2);
    int sub  = threadIdx.x & 3;
    if (node >= NN) return;
    const float4* xr = (const float4*)(x + (size_t)node * FF + sub * 32);
    float acc[HH];
#pragma unroll
    for (int c = 0; c < HH; ++c) acc[c] = 0.f;
#pragma unroll
    for (int q = 0; q < 8; ++q) {
        float4 v = xr[q];
        int k = sub * 32 + q * 4;
        const float* w0 = &sW[(k + 0) * HH];
        const float* w1 = &sW[(k + 1) * HH];
        const float* w2 = &sW[(k + 2) * HH];
        const float* w3 = &sW[(k + 3) * HH];
#pragma unroll
        for (int c = 0; c < HH; ++c)
            acc[c] += v.x * w0[c] + v.y * w1[c] + v.z * w2[c] + v.w * w3[c];
    }
#pragma unroll
    for (int c = 0; c < HH; ++c) {
        acc[c] += __shfl_xor(acc[c], 1, 64);
        acc[c] += __shfl_xor(acc[c], 2, 64);
    }
    if (sub == 0) {
        float di = dinv[node];
        half8 o;
#pragma unroll
        for (int c = 0; c < HH; ++c) o[c] = (_Float16)(di * acc[c]);
        o[6] = (_Float16)0.f; o[7] = (_Float16)0.f;
        *((half8*)(hs + (size_t)node * 8)) = o;
    }
}

// ===== fused gather + next mm, 4 lanes per node, 4-wide MLP =====
template <int HON, int HPOH>
__global__ __launch_bounds__(256) void k_gf(const int* __restrict__ rowptr,
                                            const int* __restrict__ counts,
                                            const int* __restrict__ csr,
                                            const float* __restrict__ dinv,
                                            const _Float16* __restrict__ hs,
                                            const float* __restrict__ bias,
                                            const float* __restrict__ Wn,
                                            _Float16* __restrict__ outn) {
    __shared__ float sW[HH * HON];
    if (threadIdx.x < HH * HON) sW[threadIdx.x] = Wn[threadIdx.x];
    __syncthreads();
    int node = blockIdx.x * 64 + (threadIdx.x >> 2);
    int sub  = threadIdx.x & 3;
    if (node >= NN) return;
    int st = rowptr[node], cnt = counts[node];
    float a[HH];
    if (sub == 0) {
        half8 v = *((const half8*)(hs + (size_t)node * 8));
#pragma unroll
        for (int c = 0; c < HH; ++c) a[c] = (float)v[c];
    } else {
#pragma unroll
        for (int c = 0; c < HH; ++c) a[c] = 0.f;
    }
    int j = st + sub, end = st + cnt;
    for (; j + 12 < end; j += 16) {
        int s0 = csr[j], s1 = csr[j + 4], s2 = csr[j + 8], s3 = csr[j + 12];
        half8 v0 = *((const half8*)(hs + (size_t)s0 * 8));
        half8 v1 = *((const half8*)(hs + (size_t)s1 * 8));
        half8 v2 = *((const half8*)(hs + (size_t)s2 * 8));
        half8 v3 = *((const half8*)(hs + (size_t)s3 * 8));
#pragma unroll
        for (int c = 0; c < HH; ++c)
            a[c] += ((float)v0[c] + (float)v1[c]) + ((float)v2[c] + (float)v3[c]);
    }
    for (; j < end; j += 4) {
        int s = csr[j];
        half8 v = *((const half8*)(hs + (size_t)s * 8));
#pragma unroll
        for (int c = 0; c < HH; ++c) a[c] += (float)v[c];
    }
#pragma unroll
    for (int c = 0; c < HH; ++c) {
        a[c] += __shfl_xor(a[c], 1, 64);
        a[c] += __shfl_xor(a[c], 2, 64);
    }
    if (sub == 0) {
        float di = dinv[node];
        float h[HH];
#pragma unroll
        for (int c = 0; c < HH; ++c) h[c] = fmaxf(di * a[c] + bias[c], 0.f);
        half8 o[HPOH / 8];
#pragma unroll
        for (int c = 0; c < HPOH; ++c) {
            float s = 0.f;
            if (c < HON) {
#pragma unroll
                for (int k = 0; k < HH; ++k) s += h[k] * sW[k * HON + c];
                o[c / 8][c % 8] = (_Float16)(di * s);
            } else {
                o[c / 8][c % 8] = (_Float16)0.f;
            }
        }
        half8* op = (half8*)(outn + (size_t)node * HPOH);
#pragma unroll
        for (int q = 0; q < HPOH / 8; ++q) op[q] = o[q];
    }
}

// ===== last gather: h5 = relu(dinv*(sum hs5 + self) + bf) -> f32 12-pad =====
__global__ __launch_bounds__(256) void k_glast(const int* __restrict__ rowptr,
                                               const int* __restrict__ counts,
                                               const int* __restrict__ csr,
                                               const float* __restrict__ dinv,
                                               const _Float16* __restrict__ hs,
                                               const float* __restrict__ bias,
                                               float* __restrict__ out) {
    int node = blockIdx.x * 64 + (threadIdx.x >> 2);
    int sub  = threadIdx.x & 3;
    if (node >= NN) return;
    int st = rowptr[node], cnt = counts[node];
    float a[CC];
    if (sub == 0) {
        const half8* p = (const half8*)(hs + (size_t)node * 16);
        half8 v0 = p[0], v1 = p[1];
#pragma unroll
        for (int c = 0; c < 8; ++c) a[c] = (float)v0[c];
        a[8] = (float)v1[0]; a[9] = (float)v1[1];
    } else {
#pragma unroll
        for (int c = 0; c < CC; ++c) a[c] = 0.f;
    }
    int j = st + sub, end = st + cnt;
    for (; j + 4 < end; j += 8) {
        int s0 = csr[j], s1 = csr[j + 4];
        const half8* p0 = (const half8*)(hs + (size_t)s0 * 16);
        const half8* p1 = (const half8*)(hs + (size_t)s1 * 16);
        half8 x0 = p0[0], y0 = p0[1], x1 = p1[0], y1 = p1[1];
#pragma unroll
        for (int c = 0; c < 8; ++c) a[c] += (float)x0[c] + (float)x1[c];
        a[8] += (float)y0[0] + (float)y1[0];
        a[9] += (float)y0[1] + (float)y1[1];
    }
    if (j < end) {
        int s = csr[j];
        const half8* p = (const half8*)(hs + (size_t)s * 16);
        half8 x0 = p[0], y0 = p[1];
#pragma unroll
        for (int c = 0; c < 8; ++c) a[c] += (float)x0[c];
        a[8] += (float)y0[0]; a[9] += (float)y0[1];
    }
#pragma unroll
    for (int c = 0; c < CC; ++c) {
        a[c] += __shfl_xor(a[c], 1, 64);
        a[c] += __shfl_xor(a[c], 2, 64);
    }
    if (sub == 0) {
        float di = dinv[node];
        float r[12];
#pragma unroll
        for (int c = 0; c < 12; ++c)
            r[c] = (c < CC) ? fmaxf(di * a[c] + bias[c], 0.f) : 0.f;
        float4* o = (float4*)(out + (size_t)node * 12);
        o[0] = make_float4(r[0], r[1], r[2], r[3]);
        o[1] = make_float4(r[4], r[5], r[6], r[7]);
        o[2] = make_float4(r[8], r[9], r[10], r[11]);
    }
}

// ========== pool + log_softmax, one block per graph ==========
__global__ __launch_bounds__(256) void k_pool(const float* __restrict__ h,
                                              const int* __restrict__ bounds,
                                              float* __restrict__ out) {
    int g = blockIdx.x;
    int s = bounds[g], e = bounds[g + 1];
    float acc[CC];
#pragma unroll
    for (int c = 0; c < CC; ++c) acc[c] = 0.f;
    for (int i = s + threadIdx.x; i < e; i += 256) {
#pragma unroll
        for (int c = 0; c < CC; ++c) acc[c] += h[(size_t)i * 12 + c];
    }
#pragma unroll
    for (int off = 32; off >= 1; off >>= 1)
#pragma unroll
        for (int c = 0; c < CC; ++c) acc[c] += __shfl_down(acc[c], off, 64);
    __shared__ float sacc[4][CC];
    int wv = threadIdx.x >> 6, lane = threadIdx.x & 63;
    if (lane == 0) {
#pragma unroll
        for (int c = 0; c < CC; ++c) sacc[wv][c] = acc[c];
    }
    __syncthreads();
    if (threadIdx.x == 0) {
        float cnt = fmaxf((float)(e - s), 1.0f);
        float tot[CC];
        float m = -1e30f;
#pragma unroll
        for (int c = 0; c < CC; ++c) {
            tot[c] = (sacc[0][c] + sacc[1][c] + sacc[2][c] + sacc[3][c]) / cnt;
            m = fmaxf(m, tot[c]);
        }
        float ssum = 0.f;
#pragma unroll
        for (int c = 0; c < CC; ++c) ssum += expf(tot[c] - m);
        float lse = logf(ssum) + m;
#pragma unroll
        for (int c = 0; c < CC; ++c) out[(size_t)g * CC + c] = tot[c] - lse;
    }
}

extern "C" void kernel_launch(void* const* d_in, const int* in_sizes, int n_in,
                              void* d_out, int out_size, void* d_ws, size_t ws_size,
                              hipStream_t stream) {
    const float* x     = (const float*)d_in[0];
    const int*   ei    = (const int*)d_in[1];
    const int*   batch = (const int*)d_in[2];
    const float* W1 = (const float*)d_in[3];
    const float* b1 = (const float*)d_in[4];
    const float* W2 = (const float*)d_in[5];
    const float* b2 = (const float*)d_in[6];
    const float* W3 = (const float*)d_in[7];
    const float* b3 = (const float*)d_in[8];
    const float* W4 = (const float*)d_in[9];
    const float* b4 = (const float*)d_in[10];
    const float* Wf = (const float*)d_in[11];
    const float* bf = (const float*)d_in[12];
    float* out = (float*)d_out;

    const int* src = ei;
    const int* dst = ei + EE;

    // -------- workspace layout (4B units) --------
    int*   iw     = (int*)d_ws;
    int*   csr    = iw;                        // [3,920,000] bucket-strided
    int*   rowptr = csr + 3920000;             // [100,352]
    int*   counts = rowptr + 100352;           // [100,352]
    float* dinv   = (float*)(counts + 100352); // [100,352]
    int*   gcur   = (int*)(dinv + 100352);     // [256]
    int*   bounds = gcur + 256;                // [640]
    int*   part   = bounds + 640;              // [3,920,000], overlaid after bucketfill:
    _Float16* hsA = (_Float16*)part;           //   [1,605,632 halves]
    _Float16* hsB = hsA + 1605632;             //   [1,605,632 halves]
    float* h5     = (float*)(hsB + 1605632);   //   [1,204,224 floats]

    const int TB = (EE + PTILE - 1) / PTILE;   // 391
    const int GB = (NN + 63) / 64;             // 1563 (4 lanes per node)

    // -------- CSR build --------
    k_setup<<<3, 256, 0, stream>>>(batch, gcur, bounds);
    k_partition<<<TB, 512, 0, stream>>>(src, dst, gcur, part);
    k_bucketfill<<<NBUCK, 1024, 0, stream>>>(gcur, part, csr, rowptr, counts, dinv);

    // -------- layers --------
    k_xw1<<<GB, 256, 0, stream>>>(x, W1, dinv, hsA);                                       // hs1
    k_gf<HH, 8><<<GB, 256, 0, stream>>>(rowptr, counts, csr, dinv, hsA, b1, W2, hsB);      // hs2
    k_gf<HH, 8><<<GB, 256, 0, stream>>>(rowptr, counts, csr, dinv, hsB, b2, W3, hsA);      // hs3
    k_gf<HH, 8><<<GB, 256, 0, stream>>>(rowptr, counts, csr, dinv, hsA, b3, W4, hsB);      // hs4
    k_gf<CC, 16><<<GB, 256, 0, stream>>>(rowptr, counts, csr, dinv, hsB, b4, Wf, hsA);     // hs5 (16-pad)
    k_glast<<<GB, 256, 0, stream>>>(rowptr, counts, csr, dinv, hsA, bf, h5);               // h5 f32

    // -------- pool + log_softmax --------
    k_pool<<<GG, 256, 0, stream>>>(h5, bounds, out);
}